// Round 5
// baseline (862.039 us; speedup 1.0000x reference)
//
#include <hip/hip_runtime.h>

// ---------------------------------------------------------------------------
// 2-layer hetero GraphSAGE, bipartite user<->item, H=256.
// Round 7: L3-footprint attack on the dominant layer-2 gather (209us, FETCH
// 722MB for an L3-resident working set -> random-line L3 thrash). h and B are
// now stored as two compact [N x 128] column halves; layer-2 agg runs as two
// SEQUENTIAL half-column dual dispatches (per-phase hot set 180 -> ~70 MB).
// L2 GEMM stages from the 4 half-matrices (compile-time source select); L1
// GEMM epilogue writes split h. Also: pairs packed to u32 (src<<7|row), L1
// aggs merged into one dual dispatch, both L2 GEMMs merged into one dispatch.
// CSR structure, converts, GEMM inner math unchanged from round 6.
// ---------------------------------------------------------------------------

typedef unsigned short u16;
typedef unsigned int u32;
typedef short bf16x8 __attribute__((ext_vector_type(8)));   // 8 bf16 (4 VGPRs)
typedef float f32x4 __attribute__((ext_vector_type(4)));    // MFMA acc

constexpr int HDIM = 256;
constexpr int RB = 128;       // dst rows per bucket (b = dst >> 7)
constexpr int MAXB = 784;     // max buckets: ceil(100000/128) = 782
constexpr int CHUNK = 4096;   // edges per scatter block

// ---------------- bf16 helpers ----------------

__device__ __forceinline__ float lo2f(u32 v) { union { u32 i; float f; } x; x.i = v << 16; return x.f; }
__device__ __forceinline__ float hi2f(u32 v) { union { u32 i; float f; } x; x.i = v & 0xffff0000u; return x.f; }
__device__ __forceinline__ u16 f2bf(float f) {  // RNE
    union { float f; u32 i; } x; x.f = f;
    return (u16)((x.i + 0x7fffu + ((x.i >> 16) & 1u)) >> 16);
}
__device__ __forceinline__ u32 pack2(float a, float b) {
    return (u32)f2bf(a) | ((u32)f2bf(b) << 16);
}

__device__ __forceinline__ void gload16(const void* g, void* l) {
    __builtin_amdgcn_global_load_lds(
        (const __attribute__((address_space(1))) unsigned int*)g,
        (__attribute__((address_space(3))) unsigned int*)l, 16, 0, 0);
}

// ---------------- CSR build (5 launches) ----------------

// Pass 0: per-bucket edge counts via LDS histogram.
__global__ __launch_bounds__(256) void bucket_count(const int* __restrict__ dst0, int nb0,
                                                    int* __restrict__ bc0,
                                                    const int* __restrict__ dst1, int nb1,
                                                    int* __restrict__ bc1,
                                                    int E, int sgrid) {
    __shared__ int lcnt[MAXB];
    int b = blockIdx.x;
    const int* dst; int nb; int* bc;
    if (b < sgrid) { dst = dst0; nb = nb0; bc = bc0; }
    else           { b -= sgrid; dst = dst1; nb = nb1; bc = bc1; }
    const int t = threadIdx.x;
    for (int i = t; i < nb; i += 256) lcnt[i] = 0;
    __syncthreads();
    const int base = b * CHUNK;
#pragma unroll
    for (int j = 0; j < CHUNK / 256; j++) {
        int i = base + j * 256 + t;
        if (i < E) atomicAdd(&lcnt[dst[i] >> 7], 1);
    }
    __syncthreads();
    for (int i = t; i < nb; i += 256) {
        int c = lcnt[i];
        if (c) atomicAdd(&bc[i], c);
    }
}

// Pass 1: parallel exclusive scan of bucket counts (both graphs, one block).
__global__ __launch_bounds__(1024) void bucket_scan(const int* __restrict__ bc0,
                                                    int* __restrict__ base0,
                                                    int* __restrict__ bcur0, int nb0,
                                                    const int* __restrict__ bc1,
                                                    int* __restrict__ base1,
                                                    int* __restrict__ bcur1, int nb1) {
    __shared__ int s[1024];
    const int t = threadIdx.x;
    int own = (t < nb0) ? bc0[t] : 0;
    s[t] = own;
    __syncthreads();
    for (int st = 1; st < 1024; st <<= 1) {
        int v = (t >= st) ? s[t - st] : 0;
        __syncthreads();
        s[t] += v;
        __syncthreads();
    }
    if (t < nb0) { int ex = s[t] - own; base0[t] = ex; bcur0[t] = ex; }
    if (t == 0) base0[nb0] = s[1023];
    __syncthreads();
    own = (t < nb1) ? bc1[t] : 0;
    s[t] = own;
    __syncthreads();
    for (int st = 1; st < 1024; st <<= 1) {
        int v = (t >= st) ? s[t - st] : 0;
        __syncthreads();
        s[t] += v;
        __syncthreads();
    }
    if (t < nb1) { int ex = s[t] - own; base1[t] = ex; bcur1[t] = ex; }
    if (t == 0) base1[nb1] = s[1023];
}

// Pass 2: bin edges into bucket-grouped packed runs. Payload = src<<7 | row.
__global__ __launch_bounds__(256) void binned_scatter2(
    const int* __restrict__ src0, const int* __restrict__ dst0, int nb0,
    int* __restrict__ bcur0, u32* __restrict__ pairs0,
    const int* __restrict__ src1, const int* __restrict__ dst1, int nb1,
    int* __restrict__ bcur1, u32* __restrict__ pairs1,
    int E, int sgrid) {
    __shared__ int lcnt[MAXB];
    __shared__ int lbase[MAXB];
    int b = blockIdx.x;
    const int *src, *dst; int nb; int* bcur; u32* pairs;
    if (b < sgrid) { src = src0; dst = dst0; nb = nb0; bcur = bcur0; pairs = pairs0; }
    else           { b -= sgrid; src = src1; dst = dst1; nb = nb1; bcur = bcur1; pairs = pairs1; }
    const int t = threadIdx.x;
    const int chunk = b * CHUNK;

    for (int i = t; i < nb; i += 256) lcnt[i] = 0;
    __syncthreads();

    u32 ss[CHUNK / 256], dd[CHUNK / 256];
#pragma unroll
    for (int j = 0; j < CHUNK / 256; j++) {
        int i = chunk + j * 256 + t;
        if (i < E) {
            ss[j] = (u32)src[i];
            dd[j] = (u32)dst[i];
            atomicAdd(&lcnt[dd[j] >> 7], 1);
        } else {
            ss[j] = 0; dd[j] = 0;
        }
    }
    __syncthreads();

    for (int i = t; i < nb; i += 256) {
        int c = lcnt[i];
        lbase[i] = (c > 0) ? atomicAdd(&bcur[i], c) : 0;
    }
    __syncthreads();
    for (int i = t; i < nb; i += 256) lcnt[i] = 0;  // reuse as rank counters
    __syncthreads();

#pragma unroll
    for (int j = 0; j < CHUNK / 256; j++) {
        int i = chunk + j * 256 + t;
        if (i < E) {
            int bb = (int)(dd[j] >> 7);
            int r = atomicAdd(&lcnt[bb], 1);
            pairs[(size_t)lbase[bb] + r] = (ss[j] << 7) | (dd[j] & 127u);
        }
    }
}

// Pass 3: one block per bucket: derive rp for 128 rows + fill col (LDS cursors).
__global__ __launch_bounds__(256) void bucket_fill2(
    const u32* __restrict__ pairs0, const int* __restrict__ base0, int nb0, int n0,
    int* __restrict__ rp0, int* __restrict__ col0,
    const u32* __restrict__ pairs1, const int* __restrict__ base1, int n1,
    int* __restrict__ rp1, int* __restrict__ col1) {
    __shared__ int rcnt[RB];
    __shared__ int excl[RB];
    __shared__ int lcur[RB];
    int b = blockIdx.x;
    const u32* pairs; const int* bb; int n; int* rp; int* col;
    if (b < nb0) { pairs = pairs0; bb = base0; n = n0; rp = rp0; col = col0; }
    else         { b -= nb0; pairs = pairs1; bb = base1; n = n1; rp = rp1; col = col1; }
    const int t = threadIdx.x;
    const int r0 = b * RB;
    const int e0 = bb[b], e1 = bb[b + 1];

    if (t < RB) rcnt[t] = 0;
    __syncthreads();
    for (int j = e0 + t; j < e1; j += 256) atomicAdd(&rcnt[pairs[j] & (RB - 1)], 1);
    __syncthreads();
    int own = (t < RB) ? rcnt[t] : 0;
    if (t < RB) excl[t] = own;
    __syncthreads();
    for (int st = 1; st < RB; st <<= 1) {
        int v = (t < RB && t >= st) ? excl[t - st] : 0;
        __syncthreads();
        if (t < RB) excl[t] += v;
        __syncthreads();
    }
    if (t < RB) {
        int ex = e0 + excl[t] - own;   // exclusive within bucket + bucket base
        int row = r0 + t;
        if (row < n) rp[row] = ex;
        lcur[t] = ex;
    }
    if (t == 0 && r0 + RB >= n) rp[n] = e1;  // last bucket: e1 == E
    __syncthreads();
    for (int j = e0 + t; j < e1; j += 256) {
        u32 e = pairs[j];
        int p = atomicAdd(&lcur[e & (RB - 1)], 1);
        col[p] = (int)(e >> 7);
    }
}

// ---------------- fused fp32 -> bf16 convert (all 10 tensors, 1 launch) ----

struct ConvSeg { const float* in; u16* out; u32 n4; u32 pad; };
struct ConvArgs { ConvSeg s[10]; u32 tot; };

__global__ __launch_bounds__(256) void multi_convert(ConvArgs a) {
    for (u32 i = blockIdx.x * 256 + threadIdx.x; i < a.tot; i += gridDim.x * 256) {
        u32 r = i;
        int sg = 0;
        while (r >= a.s[sg].n4) { r -= a.s[sg].n4; sg++; }
        float4 v = ((const float4*)a.s[sg].in)[r];
        ((uint2*)a.s[sg].out)[r] = make_uint2(pack2(v.x, v.y), pack2(v.z, v.w));
    }
}

// ---------------- mean aggregation: subgroup-per-row, 16B loads, depth 8 ----

template <int F>
__device__ __forceinline__ void agg_row(const u16* __restrict__ src, const int* __restrict__ rp,
                                        const int* __restrict__ col, u16* __restrict__ out,
                                        int n_dst, int d) {
    constexpr int G = F / 8;     // lanes per row
    constexpr int R = 64 / G;    // rows in flight per issue
    const int lane = threadIdx.x & 63;
    if (d >= n_dst) return;
    const int sub = lane / G;
    const int li = lane & (G - 1);
    const int e0 = rp[d], e1 = rp[d + 1];
    const size_t lo = (size_t)li * 8;   // bf16 offset of this lane's 16B chunk

    float a[8] = {0.f, 0.f, 0.f, 0.f, 0.f, 0.f, 0.f, 0.f};
    auto add8 = [&](uint4 v) {
        a[0] += lo2f(v.x); a[1] += hi2f(v.x);
        a[2] += lo2f(v.y); a[3] += hi2f(v.y);
        a[4] += lo2f(v.z); a[5] += hi2f(v.z);
        a[6] += lo2f(v.w); a[7] += hi2f(v.w);
    };

    int ebase = e0;
    for (; ebase + 8 * R <= e1; ebase += 8 * R) {
        int c[8];
#pragma unroll
        for (int k = 0; k < 8; k++) c[k] = col[ebase + sub + k * R];
        uint4 v[8];
#pragma unroll
        for (int k = 0; k < 8; k++) v[k] = *(const uint4*)(src + (size_t)c[k] * F + lo);
#pragma unroll
        for (int k = 0; k < 8; k++) add8(v[k]);
    }
    for (; ebase + 4 * R <= e1; ebase += 4 * R) {
        int c[4];
#pragma unroll
        for (int k = 0; k < 4; k++) c[k] = col[ebase + sub + k * R];
        uint4 v[4];
#pragma unroll
        for (int k = 0; k < 4; k++) v[k] = *(const uint4*)(src + (size_t)c[k] * F + lo);
#pragma unroll
        for (int k = 0; k < 4; k++) add8(v[k]);
    }
    for (int e = ebase + sub; e < e1; e += R) {
        uint4 v = *(const uint4*)(src + (size_t)col[e] * F + lo);
        add8(v);
    }

#pragma unroll
    for (int m = G; m < 64; m <<= 1) {
#pragma unroll
        for (int j = 0; j < 8; j++) a[j] += __shfl_xor(a[j], m, 64);
    }

    const int deg = e1 - e0;
    const float inv = (deg > 0) ? 1.f / (float)deg : 0.f;
    if (lane < G) {
        uint4 w;
        w.x = pack2(a[0] * inv, a[1] * inv);
        w.y = pack2(a[2] * inv, a[3] * inv);
        w.z = pack2(a[4] * inv, a[5] * inv);
        w.w = pack2(a[6] * inv, a[7] * inv);
        *(uint4*)(out + (size_t)d * F + lo) = w;
    }
}

// two independent aggregations in one dispatch (block-range split)
template <int F0, int F1>
__global__ __launch_bounds__(256) void agg_dual(
    const u16* __restrict__ src0, const int* __restrict__ rp0, const int* __restrict__ col0,
    u16* __restrict__ out0, int n0, int g0,
    const u16* __restrict__ src1, const int* __restrict__ rp1, const int* __restrict__ col1,
    u16* __restrict__ out1, int n1) {
    const int b = blockIdx.x;
    if (b < g0) agg_row<F0>(src0, rp0, col0, out0, n0, b * 4 + (threadIdx.x >> 6));
    else        agg_row<F1>(src1, rp1, col1, out1, n1, (b - g0) * 4 + (threadIdx.x >> 6));
}

// ---------------- MFMA GEMM, m97 structure ----------------
// mfma_f32_16x16x32_bf16 layouts (HW-verified):
//   A: lane holds A[m=lane&15][k=ql*8+j]
//   B: lane holds B[k=ql*8+j][n=lane&15] = W[n][k]
//   C/D: col=lane&15, row=ql*4+reg

// Layer-1 GEMM: h = relu([A | X] @ [WA | WB]^T + bias), h written as two
// [M x 128] column halves (outLo / outHi).
template <int KA, int KB>
__global__ __launch_bounds__(256, 3) void gemm_l1(const u16* __restrict__ A,
                                                  const u16* __restrict__ X,
                                                  const u16* __restrict__ WA,
                                                  const u16* __restrict__ WB,
                                                  const float* __restrict__ bias,
                                                  u16* __restrict__ outLo,
                                                  u16* __restrict__ outHi, int M) {
    constexpr int KT = KA + KB;
    constexpr int NKT = KT / 32;
    __shared__ __align__(16) u16 Al[128 * 32];
    __shared__ __align__(16) u16 Wl[128 * 32];

    // XCD-aware bijective swizzle (m204)
    const int nwg = gridDim.x;
    const int b = blockIdx.x;
    const int q = nwg >> 3, r = nwg & 7;
    const int xcd = b & 7, within = b >> 3;
    const int logical = (xcd < r ? xcd * (q + 1) : r * (q + 1) + (xcd - r) * q) + within;
    const int mb = logical >> 1;
    const int nb = logical & 1;
    const int row0 = mb * 128;
    const int ncol0 = nb * 128;

    const int tid = threadIdx.x;
    const int lane = tid & 63;
    const int wid = tid >> 6;
    const int wr = wid >> 1;
    const int wc = wid & 1;
    const int ml = lane & 15;
    const int ql = lane >> 4;
    const int lrow4 = lane >> 2;
    const int lcol8 = (lane & 3) * 8;

    f32x4 acc[4][4];
#pragma unroll
    for (int m = 0; m < 4; m++)
#pragma unroll
        for (int n = 0; n < 4; n++) acc[m][n] = {0.f, 0.f, 0.f, 0.f};

    const int s0 = wid * 2;

#pragma unroll
    for (int kt = 0; kt < NKT; ++kt) {
        const int kk = kt * 32;
#pragma unroll
        for (int j = 0; j < 2; ++j) {
            const int s = s0 + j;
            int gr = row0 + s * 16 + lrow4;
            gr = (gr < M) ? gr : (M - 1);
            const u16* gp = (kk < KA) ? (A + (size_t)gr * KA + (kk + lcol8))
                                      : (X + (size_t)gr * KB + (kk - KA + lcol8));
            gload16(gp, &Al[s * 512]);
        }
#pragma unroll
        for (int j = 0; j < 2; ++j) {
            const int s = s0 + j;
            const int gn = ncol0 + s * 16 + lrow4;
            const u16* gp = (kk < KA) ? (WA + (size_t)gn * KA + (kk + lcol8))
                                      : (WB + (size_t)gn * KB + (kk - KA + lcol8));
            gload16(gp, &Wl[s * 512]);
        }
        __syncthreads();

        bf16x8 af[4], wf[4];
#pragma unroll
        for (int m = 0; m < 4; m++)
            af[m] = *(const bf16x8*)&Al[(wr * 64 + m * 16 + ml) * 32 + ql * 8];
#pragma unroll
        for (int n = 0; n < 4; n++)
            wf[n] = *(const bf16x8*)&Wl[(wc * 64 + n * 16 + ml) * 32 + ql * 8];
#pragma unroll
        for (int m = 0; m < 4; m++)
#pragma unroll
            for (int n = 0; n < 4; n++)
                acc[m][n] = __builtin_amdgcn_mfma_f32_16x16x32_bf16(af[m], wf[n], acc[m][n], 0, 0, 0);
        __syncthreads();
    }

#pragma unroll
    for (int n = 0; n < 4; n++) {
        const int gcol = ncol0 + wc * 64 + n * 16 + ml;
        const float bv = bias[gcol];
        u16* ob; int cw;
        if (gcol < 128) { ob = outLo; cw = gcol; }
        else            { ob = outHi; cw = gcol - 128; }
#pragma unroll
        for (int m = 0; m < 4; m++) {
            const int gr0 = row0 + wr * 64 + m * 16 + ql * 4;
#pragma unroll
            for (int rr = 0; rr < 4; rr++) {
                const int grow = gr0 + rr;
                if (grow >= M) continue;
                float v = fmaxf(acc[m][n][rr] + bv, 0.f);
                ob[(size_t)grow * 128 + cw] = f2bf(v);
            }
        }
    }
}

// Layer-2 GEMM: out = [B_lo|B_hi|h_lo|h_hi] @ [WA|WB]^T + bias, fp32 out.
// Both (item, user) problems merged into one dispatch via block-range split.
struct GemmSet {
    const u16* p0; const u16* p1; const u16* p2; const u16* p3;  // 4x [M x 128]
    const u16* WA; const u16* WB;                                 // [256 x 256]
    const float* bias; float* out; int M; int pad;
};
struct GemmL2Args { GemmSet s[2]; int g0; };

__global__ __launch_bounds__(256, 3) void gemm_l2(GemmL2Args a) {
    __shared__ __align__(16) u16 Al[128 * 32];
    __shared__ __align__(16) u16 Wl[128 * 32];

    // XCD-aware bijective swizzle over the merged grid
    const int nwg = gridDim.x;
    const int b = blockIdx.x;
    const int q = nwg >> 3, r = nwg & 7;
    const int xcd = b & 7, within = b >> 3;
    int logical = (xcd < r ? xcd * (q + 1) : r * (q + 1) + (xcd - r) * q) + within;
    const GemmSet& S = (logical < a.g0) ? a.s[0] : a.s[1];
    if (logical >= a.g0) logical -= a.g0;
    const int mb = logical >> 1;
    const int nb = logical & 1;
    const int row0 = mb * 128;
    const int ncol0 = nb * 128;
    const int M = S.M;
    const u16* srcs[4] = {S.p0, S.p1, S.p2, S.p3};

    const int tid = threadIdx.x;
    const int lane = tid & 63;
    const int wid = tid >> 6;
    const int wr = wid >> 1;
    const int wc = wid & 1;
    const int ml = lane & 15;
    const int ql = lane >> 4;
    const int lrow4 = lane >> 2;
    const int lcol8 = (lane & 3) * 8;

    f32x4 acc[4][4];
#pragma unroll
    for (int m = 0; m < 4; m++)
#pragma unroll
        for (int n = 0; n < 4; n++) acc[m][n] = {0.f, 0.f, 0.f, 0.f};

    const int s0 = wid * 2;

#pragma unroll
    for (int kt = 0; kt < 16; ++kt) {
        const int kk = kt * 32;
        const int sel = kt >> 2;       // which [M x 128] source
        const int off = kk & 127;      // col within source
#pragma unroll
        for (int j = 0; j < 2; ++j) {
            const int s = s0 + j;
            int gr = row0 + s * 16 + lrow4;
            gr = (gr < M) ? gr : (M - 1);
            gload16(srcs[sel] + (size_t)gr * 128 + off + lcol8, &Al[s * 512]);
        }
#pragma unroll
        for (int j = 0; j < 2; ++j) {
            const int s = s0 + j;
            const int gn = ncol0 + s * 16 + lrow4;
            const u16* wp = (kt < 8) ? (S.WA + (size_t)gn * 256 + kk + lcol8)
                                     : (S.WB + (size_t)gn * 256 + (kk - 256 + lcol8));
            gload16(wp, &Wl[s * 512]);
        }
        __syncthreads();

        bf16x8 af[4], wf[4];
#pragma unroll
        for (int m = 0; m < 4; m++)
            af[m] = *(const bf16x8*)&Al[(wr * 64 + m * 16 + ml) * 32 + ql * 8];
#pragma unroll
        for (int n = 0; n < 4; n++)
            wf[n] = *(const bf16x8*)&Wl[(wc * 64 + n * 16 + ml) * 32 + ql * 8];
#pragma unroll
        for (int m = 0; m < 4; m++)
#pragma unroll
            for (int n = 0; n < 4; n++)
                acc[m][n] = __builtin_amdgcn_mfma_f32_16x16x32_bf16(af[m], wf[n], acc[m][n], 0, 0, 0);
        __syncthreads();
    }

#pragma unroll
    for (int n = 0; n < 4; n++) {
        const int gcol = ncol0 + wc * 64 + n * 16 + ml;
        const float bv = S.bias[gcol];
#pragma unroll
        for (int m = 0; m < 4; m++) {
            const int gr0 = row0 + wr * 64 + m * 16 + ql * 4;
#pragma unroll
            for (int rr = 0; rr < 4; rr++) {
                const int grow = gr0 + rr;
                if (grow >= M) continue;
                S.out[(size_t)grow * HDIM + gcol] = acc[m][n][rr] + bv;
            }
        }
    }
}

// ---------------- host ----------------

extern "C" void kernel_launch(void* const* d_in, const int* in_sizes, int n_in,
                              void* d_out, int out_size, void* d_ws, size_t ws_size,
                              hipStream_t stream) {
    const float* x_user = (const float*)d_in[0];
    const float* x_item = (const float*)d_in[1];
    const int* eui_src = (const int*)d_in[2];
    const int* eui_dst = (const int*)d_in[3];
    const int* eiu_src = (const int*)d_in[4];
    const int* eiu_dst = (const int*)d_in[5];
    const float* W1l_ui = (const float*)d_in[6];
    const float* b1_ui  = (const float*)d_in[7];
    const float* W1r_ui = (const float*)d_in[8];
    const float* W1l_iu = (const float*)d_in[9];
    const float* b1_iu  = (const float*)d_in[10];
    const float* W1r_iu = (const float*)d_in[11];
    const float* W2l_ui = (const float*)d_in[12];
    const float* b2_ui  = (const float*)d_in[13];
    const float* W2r_ui = (const float*)d_in[14];
    const float* W2l_iu = (const float*)d_in[15];
    const float* b2_iu  = (const float*)d_in[16];
    const float* W2r_iu = (const float*)d_in[17];

    const int DU = 128, DI = 64;
    const int NU = in_sizes[0] / DU;   // 100000
    const int NI = in_sizes[1] / DI;   // 50000
    const int E  = in_sizes[2];        // 1600000

    // ---- carve workspace (256B aligned) ----
    char* base = (char*)d_ws;
    size_t off = 0;
    auto carve = [&](size_t bytes) -> char* {
        char* p = base + off;
        off += (bytes + 255) & ~(size_t)255;
        return p;
    };
    int* rp_i   = (int*)carve((size_t)(NI + 1) * 4);
    int* rp_u   = (int*)carve((size_t)(NU + 1) * 4);
    int* col_ui = (int*)carve((size_t)E * 4);
    int* col_iu = (int*)carve((size_t)E * 4);
    int* bc     = (int*)carve((size_t)2 * MAXB * 4);
    int* bc_i   = bc;
    int* bc_u   = bc + MAXB;
    int* base_i = (int*)carve((size_t)(MAXB + 1) * 4);
    int* base_u = (int*)carve((size_t)(MAXB + 1) * 4);
    int* bcur_i = (int*)carve(MAXB * 4);
    int* bcur_u = (int*)carve(MAXB * 4);
    // bf16 weights
    u16* W1l_ui_b = (u16*)carve((size_t)HDIM * DU * 2);
    u16* W1r_ui_b = (u16*)carve((size_t)HDIM * DI * 2);
    u16* W1l_iu_b = (u16*)carve((size_t)HDIM * DI * 2);
    u16* W1r_iu_b = (u16*)carve((size_t)HDIM * DU * 2);
    u16* W2l_ui_b = (u16*)carve((size_t)HDIM * HDIM * 2);
    u16* W2r_ui_b = (u16*)carve((size_t)HDIM * HDIM * 2);
    u16* W2l_iu_b = (u16*)carve((size_t)HDIM * HDIM * 2);
    u16* W2r_iu_b = (u16*)carve((size_t)HDIM * HDIM * 2);
    // slot1 (25.6 MB): x_user_bf [NUx128]; later B_i_lo + B_i_hi (2x 12.8 MB)
    char* slot1 = carve((size_t)NU * DU * 2);
    u16* x_user_b = (u16*)slot1;
    u16* B_i_lo   = (u16*)slot1;
    u16* B_i_hi   = (u16*)(slot1 + (size_t)NI * 128 * 2);
    // slotB (51.2 MB): x_item_bf + A_i + A_u; later B_u_lo + B_u_hi (2x 25.6 MB)
    char* slotB = carve((size_t)NU * HDIM * 2);
    u16* x_item_b = (u16*)slotB;                               // NI*64*2  = 6.4 MB
    u16* A_i      = (u16*)(slotB + (size_t)NI * DI * 2);       // NI*128*2 = 12.8 MB
    u16* A_u      = (u16*)(slotB + (size_t)NI * DI * 2 + (size_t)NI * DU * 2);  // NU*64*2
    u16* B_u_lo   = (u16*)slotB;
    u16* B_u_hi   = (u16*)(slotB + (size_t)NU * 128 * 2);
    // h buffers, column-blocked halves (persist through layer 2)
    u16* h_item_lo = (u16*)carve((size_t)NI * 128 * 2);  // 12.8 MB
    u16* h_item_hi = (u16*)carve((size_t)NI * 128 * 2);  // 12.8 MB
    u16* h_user_lo = (u16*)carve((size_t)NU * 128 * 2);  // 25.6 MB
    u16* h_user_hi = (u16*)carve((size_t)NU * 128 * 2);  // 25.6 MB

    // packed pairs scratch (2 x 6.4 MB) aliases h_user_lo: dead until L1 gemm
    u32* pairs_i = (u32*)h_user_lo;
    u32* pairs_u = pairs_i + E;

    float* out_user = (float*)d_out;
    float* out_item = (float*)d_out + (size_t)NU * HDIM;

    const int nb_i = (NI + RB - 1) / RB;   // 391
    const int nb_u = (NU + RB - 1) / RB;   // 782
    const int sgrid = (E + CHUNK - 1) / CHUNK;

    // ---- CSR build ----
    hipMemsetAsync(bc, 0, (size_t)2 * MAXB * 4, stream);
    bucket_count<<<2 * sgrid, 256, 0, stream>>>(eui_dst, nb_i, bc_i, eiu_dst, nb_u, bc_u, E, sgrid);
    bucket_scan<<<1, 1024, 0, stream>>>(bc_i, base_i, bcur_i, nb_i, bc_u, base_u, bcur_u, nb_u);
    binned_scatter2<<<2 * sgrid, 256, 0, stream>>>(
        eui_src, eui_dst, nb_i, bcur_i, pairs_i,
        eiu_src, eiu_dst, nb_u, bcur_u, pairs_u, E, sgrid);
    bucket_fill2<<<nb_i + nb_u, 256, 0, stream>>>(
        pairs_i, base_i, nb_i, NI, rp_i, col_ui,
        pairs_u, base_u, NU, rp_u, col_iu);

    // ---- converts (1 launch) ----
    {
        ConvArgs ca;
        auto seg = [&](int i, const float* in, u16* outp, size_t n) {
            ca.s[i].in = in; ca.s[i].out = outp; ca.s[i].n4 = (u32)(n / 4); ca.s[i].pad = 0;
        };
        seg(0, x_user, x_user_b, (size_t)NU * DU);
        seg(1, x_item, x_item_b, (size_t)NI * DI);
        seg(2, W2l_ui, W2l_ui_b, (size_t)HDIM * HDIM);
        seg(3, W2r_ui, W2r_ui_b, (size_t)HDIM * HDIM);
        seg(4, W2l_iu, W2l_iu_b, (size_t)HDIM * HDIM);
        seg(5, W2r_iu, W2r_iu_b, (size_t)HDIM * HDIM);
        seg(6, W1l_ui, W1l_ui_b, (size_t)HDIM * DU);
        seg(7, W1r_ui, W1r_ui_b, (size_t)HDIM * DI);
        seg(8, W1l_iu, W1l_iu_b, (size_t)HDIM * DI);
        seg(9, W1r_iu, W1r_iu_b, (size_t)HDIM * DU);
        u32 tot = 0;
        for (int i = 0; i < 10; i++) tot += ca.s[i].n4;
        ca.tot = tot;
        multi_convert<<<2048, 256, 0, stream>>>(ca);
    }

    const int gi = (NI + 3) / 4;   // agg blocks, item-dst
    const int gu = (NU + 3) / 4;   // agg blocks, user-dst

    // ---- layer 1 ----
    agg_dual<128, 64><<<gi + gu, 256, 0, stream>>>(
        x_user_b, rp_i, col_ui, A_i, NI, gi,
        x_item_b, rp_u, col_iu, A_u, NU);
    gemm_l1<128, 64><<<((NI + 127) / 128) * 2, 256, 0, stream>>>(
        A_i, x_item_b, W1l_ui_b, W1r_ui_b, b1_ui, h_item_lo, h_item_hi, NI);
    gemm_l1<64, 128><<<((NU + 127) / 128) * 2, 256, 0, stream>>>(
        A_u, x_user_b, W1l_iu_b, W1r_iu_b, b1_iu, h_user_lo, h_user_hi, NU);

    // ---- layer 2 ----
    // agg halves sequentially: per-phase L3 footprint ~70 MB instead of ~180.
    // (B_i_* overwrites x_user_b; B_u_* overwrites x_item/A_i/A_u: all dead)
    agg_dual<128, 128><<<gi + gu, 256, 0, stream>>>(
        h_user_lo, rp_i, col_ui, B_i_lo, NI, gi,
        h_item_lo, rp_u, col_iu, B_u_lo, NU);
    agg_dual<128, 128><<<gi + gu, 256, 0, stream>>>(
        h_user_hi, rp_i, col_ui, B_i_hi, NI, gi,
        h_item_hi, rp_u, col_iu, B_u_hi, NU);
    {
        GemmL2Args ga;
        ga.s[0].p0 = B_i_lo; ga.s[0].p1 = B_i_hi; ga.s[0].p2 = h_item_lo; ga.s[0].p3 = h_item_hi;
        ga.s[0].WA = W2l_ui_b; ga.s[0].WB = W2r_ui_b; ga.s[0].bias = b2_ui;
        ga.s[0].out = out_item; ga.s[0].M = NI; ga.s[0].pad = 0;
        ga.s[1].p0 = B_u_lo; ga.s[1].p1 = B_u_hi; ga.s[1].p2 = h_user_lo; ga.s[1].p3 = h_user_hi;
        ga.s[1].WA = W2l_iu_b; ga.s[1].WB = W2r_iu_b; ga.s[1].bias = b2_iu;
        ga.s[1].out = out_user; ga.s[1].M = NU; ga.s[1].pad = 0;
        int g0 = ((NI + 127) / 128) * 2;
        int g1 = ((NU + 127) / 128) * 2;
        ga.g0 = g0;
        gemm_l2<<<g0 + g1, 256, 0, stream>>>(ga);
    }
}